// Round 1
// 176.330 us; speedup vs baseline: 1.0785x; 1.0785x over previous
//
#include <hip/hip_runtime.h>
#include <hip/hip_bf16.h>
#include <cstdint>
#include <cstddef>

// Problem constants (from reference setup_inputs)
#define HH   16
#define BB   4
#define NN   4096
#define DD   1024
#define MM   (BB * NN)      // 16384 rows
#define NC   128            // scan chunks
#define LC   32             // chunk length (NC*LC == NN)
#define EPSV 1e-6f

typedef short short8 __attribute__((ext_vector_type(8)));   // 8 x bf16 (4 VGPRs)
typedef float floatx4 __attribute__((ext_vector_type(4)));

__device__ __forceinline__ void async_copy16(const void* g, void* l) {
    __builtin_amdgcn_global_load_lds(
        (const __attribute__((address_space(1))) void*)g,
        (__attribute__((address_space(3))) void*)l, 16, 0, 0);
}

__device__ __forceinline__ uint2 pack_bf16x4(float a, float b, float c, float d) {
    union { __hip_bfloat16 h[4]; uint2 u; } cv;
    cv.h[0] = __float2bfloat16(a); cv.h[1] = __float2bfloat16(b);
    cv.h[2] = __float2bfloat16(c); cv.h[3] = __float2bfloat16(d);
    return cv.u;
}

// ---- meta: lam[h] = sigmoid(log_decay[h]); c[h] = dot(qh, kh) -------------
__global__ void k_meta(const float* __restrict__ q, const float* __restrict__ k,
                       const float* __restrict__ ld, float* __restrict__ meta) {
    int tid = threadIdx.x;              // 1024 threads; wave w == head w
    float p = q[tid] * k[tid];
    #pragma unroll
    for (int off = 32; off > 0; off >>= 1) p += __shfl_xor(p, off);
    if ((tid & 63) == 0) meta[16 + (tid >> 6)] = p;
    if (tid < HH) meta[tid] = 1.f / (1.f + expf(-ld[tid]));
}

// ---- W'[i,j] = o_w[i,j] * nw[j]  (bf16), float4 vectorized ---------------
__global__ void k_wconv(const float* __restrict__ ow, const float* __restrict__ nw,
                        __hip_bfloat16* __restrict__ wp) {
    size_t i4 = (size_t)blockIdx.x * 256 + threadIdx.x;  // over D*D/4
    int j = (int)((i4 * 4) & (DD - 1));
    float4 v = ((const float4*)ow)[i4];
    ((uint2*)wp)[i4] = pack_bf16x4(v.x * nw[j], v.y * nw[j + 1],
                                   v.z * nw[j + 2], v.w * nw[j + 3]);
}

// ---- pass A: chunk-local scan end values (float4 per thread) --------------
__global__ void k_chunk_end(const float* __restrict__ x, const float* __restrict__ meta,
                            float* __restrict__ E) {
    int b = blockIdx.x >> 7, c = blockIdx.x & (NC - 1);
    int j4 = threadIdx.x;                // float4 channel group 0..255
    float lam = meta[(j4 * 4) >> 6];     // 4-ch group never crosses a head
    const float4* xp = (const float4*)(x + ((size_t)(b * NN + c * LC)) * DD) + j4;
    float4 e = {0.f, 0.f, 0.f, 0.f};
    #pragma unroll
    for (int t = 0; t < LC; ++t) {
        float4 v = xp[(size_t)t * (DD / 4)];
        e.x = fmaf(lam, e.x, v.x); e.y = fmaf(lam, e.y, v.y);
        e.z = fmaf(lam, e.z, v.z); e.w = fmaf(lam, e.w, v.w);
    }
    ((float4*)(E + (size_t)blockIdx.x * DD))[j4] = e;
}

// ---- pass B: carry prefix via LDS transpose (coalesced global access) -----
__global__ void k_carry(const float* __restrict__ meta, const float* __restrict__ E,
                        float* __restrict__ P) {
    __shared__ float tile[NC][33];       // +1 pad
    int b = blockIdx.x >> 5, jg = blockIdx.x & 31;   // 4 b x 32 j-groups
    int tid = threadIdx.x;               // 256 threads
    int cc = tid >> 5, jj = tid & 31;
    #pragma unroll
    for (int it = 0; it < 16; ++it) {
        int c = it * 8 + cc;
        tile[c][jj] = E[(size_t)(b * NC + c) * DD + jg * 32 + jj];
    }
    __syncthreads();
    if (tid < 32) {
        int j = jg * 32 + tid;           // 32-ch group never crosses a head
        float lam = meta[j >> 6];
        float lamL = lam;                // lam^32 via 5 squarings
        lamL *= lamL; lamL *= lamL; lamL *= lamL; lamL *= lamL; lamL *= lamL;
        float p = 0.f;
        for (int c = 0; c < NC; ++c) {
            float e = tile[c][tid];
            tile[c][tid] = p;            // carry INTO chunk c
            p = fmaf(lamL, p, e);
        }
    }
    __syncthreads();
    #pragma unroll
    for (int it = 0; it < 16; ++it) {
        int c = it * 8 + cc;
        P[(size_t)(b * NC + c) * DD + jg * 32 + jj] = tile[c][jj];
    }
}

// ---- pass C: full scan w/ carry, scale, bf16 store, row sum-sq ------------
// Each block exclusively owns rows [row0, row0+32): no atomics, no memset.
__global__ void k_scan(const float* __restrict__ x, const float* __restrict__ meta,
                       const float* __restrict__ P, __hip_bfloat16* __restrict__ obf,
                       float* __restrict__ sumsq) {
    __shared__ float ssq[4][LC];
    int b = blockIdx.x >> 7, c = blockIdx.x & (NC - 1);
    int j4 = threadIdx.x;                // 0..255
    int h = (j4 * 4) >> 6;
    float lam = meta[h];
    float ch  = meta[16 + h];
    int row0 = b * NN + c * LC;
    int lane = threadIdx.x & 63, w = threadIdx.x >> 6;
    const float4* xp = (const float4*)(x + (size_t)row0 * DD) + j4;
    float4 y = ((const float4*)(P + (size_t)blockIdx.x * DD))[j4];
    for (int t = 0; t < LC; ++t) {
        float4 v = xp[(size_t)t * (DD / 4)];
        y.x = fmaf(lam, y.x, v.x); y.y = fmaf(lam, y.y, v.y);
        y.z = fmaf(lam, y.z, v.z); y.w = fmaf(lam, y.w, v.w);
        float ox = ch * y.x, oy = ch * y.y, oz = ch * y.z, ow = ch * y.w;
        ((uint2*)(obf + (size_t)(row0 + t) * DD))[j4] = pack_bf16x4(ox, oy, oz, ow);
        float s = ox * ox + oy * oy + oz * oz + ow * ow;
        #pragma unroll
        for (int off = 32; off > 0; off >>= 1) s += __shfl_xor(s, off);
        if (lane == 0) ssq[w][t] = s;
    }
    __syncthreads();
    if (threadIdx.x < LC) {
        int t = threadIdx.x;
        sumsq[row0 + t] = ssq[0][t] + ssq[1][t] + ssq[2][t] + ssq[3][t];
    }
}

// ---- GEMM: out[m,i] = rs[m] * sum_j A[m,j] * W'[i,j] ----------------------
// 256x256 tile, BK=64, 512 threads (8 waves, 2x4), double-buffered LDS with
// COUNTED vmcnt (never drains to 0 in steady state), kk-half staging order,
// 2-bit XOR bank swizzle (inverse-swizzled global source, linear LDS dest),
// s_setprio around MFMA clusters, XCD-grouped bm mapping.
//
// LDS layout per [buf][mat][kk] half: row-major [256 rows][4 octets][8 bf16];
// LDS octet position p holds global octet (kk*4 + (p ^ ((row>>1)&3))).
// Per-phase sync: s_waitcnt vmcnt(4) + raw s_barrier — the most-recently
// issued half-tile's 4 loads stay in flight across the barrier.
#define GEMM_STAGE(BUF, MAT, KK, TN)                                           \
  do {                                                                         \
    const short* _src = (MAT) ? Wg : Ag;                                       \
    const int _b0 = (MAT) ? n0 : m0;                                           \
    char* _dst = (char*)&lds[BUF][MAT][KK][0] + w * 1024;                      \
    _Pragma("unroll") for (int _i = 0; _i < 2; ++_i)                           \
      async_copy16(_src + (size_t)(_b0 + _i * 128 + rr) * 1024                 \
                        + (TN) * 64 + (KK) * 32 + oo * 8,                      \
                   _dst + _i * 8192);                                          \
  } while (0)

#define GEMM_REGION(BUF, KK)                                                   \
  do {                                                                         \
    short8 af[8]; short8 bf[4];                                                \
    _Pragma("unroll") for (int mt = 0; mt < 8; ++mt)                           \
      af[mt] = *(const short8*)(&lds[BUF][0][KK][0] +                          \
                                (arow_base + mt * 16) * 32 + p_rd * 8);        \
    _Pragma("unroll") for (int nt = 0; nt < 4; ++nt)                           \
      bf[nt] = *(const short8*)(&lds[BUF][1][KK][0] +                          \
                                (brow_base + nt * 16) * 32 + p_rd * 8);        \
    __builtin_amdgcn_s_setprio(1);                                             \
    _Pragma("unroll") for (int mt = 0; mt < 8; ++mt) {                         \
      _Pragma("unroll") for (int nt = 0; nt < 4; ++nt)                         \
        acc[mt][nt] = __builtin_amdgcn_mfma_f32_16x16x32_bf16(                 \
            af[mt], bf[nt], acc[mt][nt], 0, 0, 0);                             \
    }                                                                          \
    __builtin_amdgcn_s_setprio(0);                                             \
  } while (0)

__launch_bounds__(512, 2)
__global__ void k_gemm(const __hip_bfloat16* __restrict__ A,
                       const __hip_bfloat16* __restrict__ W,
                       const float* __restrict__ sumsq, float* __restrict__ out) {
    // [buf][mat(A=0,B=1)][kk][256 rows * 4 octets * 8 shorts] = 128 KiB total
    __shared__ __attribute__((aligned(16))) short lds[2][2][2][256 * 32];
    const int tid = threadIdx.x;
    const int lane = tid & 63, w = tid >> 6;
    const int wm = w >> 2, wn = w & 3;           // 2x4 wave grid, 128x64 each
    const int g = blockIdx.x;                    // 256 blocks = 1 per CU
    const int xcd = g & 7, idx = g >> 3;
    const int bm = xcd * 8 + (idx >> 2);         // 4 bn-blocks of a bm share an XCD
    const int bn = idx & 3;
    const int m0 = bm * 256, n0 = bn * 256;
    const short* Ag = (const short*)A;
    const short* Wg = (const short*)W;

    // staging geometry: slot s = i*512 + tid; row r = s>>2, octet pos p = s&3;
    // global octet o = p ^ ((r>>1)&3)  (same for i=0,1 since 128 ≡ 0 mod 4 after >>1)
    const int rr = tid >> 2;                     // 0..127
    const int oo = (tid & 3) ^ ((rr >> 1) & 3);

    // read-side swizzled octet (frag row base is a multiple of 16)
    const int p_rd = (lane >> 4) ^ (((lane & 15) >> 1) & 3);
    const int arow_base = wm * 128 + (lane & 15);
    const int brow_base = wn * 64 + (lane & 15);

    floatx4 acc[8][4] = {};

    // prologue: stage all 4 halves of K-tile 0 (8 loads/thread outstanding)
    GEMM_STAGE(0, 0, 0, 0); GEMM_STAGE(0, 1, 0, 0);
    GEMM_STAGE(0, 0, 1, 0); GEMM_STAGE(0, 1, 1, 0);

    for (int t = 0; t < 16; ++t) {
        const int buf = t & 1;
        // entry checkpoint: oldest 4 loads (this tile's kk0 halves) complete;
        // this tile's kk1 halves may still be in flight.
        asm volatile("s_waitcnt vmcnt(4)" ::: "memory");
        __builtin_amdgcn_s_barrier();
        if (t < 15) { GEMM_STAGE(buf ^ 1, 0, 0, t + 1); GEMM_STAGE(buf ^ 1, 1, 0, t + 1); }
        GEMM_REGION(buf, 0);
        // mid checkpoint: this tile's kk1 halves complete; next tile's kk0
        // halves (just issued) stay in flight.
        if (t < 15) {
            asm volatile("s_waitcnt vmcnt(4)" ::: "memory");
        } else {
            asm volatile("s_waitcnt vmcnt(0)" ::: "memory");
        }
        __builtin_amdgcn_s_barrier();
        if (t < 15) { GEMM_STAGE(buf ^ 1, 0, 1, t + 1); GEMM_STAGE(buf ^ 1, 1, 1, t + 1); }
        GEMM_REGION(buf, 1);
    }

    // epilogue: RMSNorm scale + store. D[m,n]: row = (l>>4)*4+reg, col = l&15
    #pragma unroll
    for (int mt = 0; mt < 8; ++mt) {
        #pragma unroll
        for (int r = 0; r < 4; ++r) {
            int mrow = m0 + wm * 128 + mt * 16 + (lane >> 4) * 4 + r;
            float rs = rsqrtf(sumsq[mrow] * (1.f / 1024.f) + EPSV);
            #pragma unroll
            for (int nt = 0; nt < 4; ++nt) {
                int col = n0 + wn * 64 + nt * 16 + (lane & 15);
                out[(size_t)mrow * 1024 + col] = acc[mt][nt][r] * rs;
            }
        }
    }
}

extern "C" void kernel_launch(void* const* d_in, const int* in_sizes, int n_in,
                              void* d_out, int out_size, void* d_ws, size_t ws_size,
                              hipStream_t stream) {
    const float* x  = (const float*)d_in[0];
    const float* q  = (const float*)d_in[1];
    const float* k  = (const float*)d_in[2];
    const float* ld = (const float*)d_in[3];
    const float* nw = (const float*)d_in[4];
    const float* ow = (const float*)d_in[5];
    float* out = (float*)d_out;

    char* ws = (char*)d_ws;
    // layout (256B aligned): meta[32]f | sumsq[M]f | E f | P f | W' bf16 | O bf16
    float* meta  = (float*)(ws + 0);
    float* sumsq = (float*)(ws + 256);
    float* E     = (float*)(ws + 65792);
    float* P     = (float*)(ws + 2162944);
    __hip_bfloat16* Wp  = (__hip_bfloat16*)(ws + 4260096);
    __hip_bfloat16* Obf = (__hip_bfloat16*)(ws + 6357248);

    k_meta<<<1, 1024, 0, stream>>>(q, k, ld, meta);
    k_wconv<<<(DD * DD / 4) / 256, 256, 0, stream>>>(ow, nw, Wp);
    k_chunk_end<<<BB * NC, 256, 0, stream>>>(x, meta, E);
    k_carry<<<BB * 32, 256, 0, stream>>>(meta, E, P);
    k_scan<<<BB * NC, 256, 0, stream>>>(x, meta, P, Obf, sumsq);
    k_gemm<<<(MM / 256) * (DD / 256), 512, 0, stream>>>(Obf, Wp, sumsq, out);
}

// Round 2
// 174.275 us; speedup vs baseline: 1.0912x; 1.0118x over previous
//
#include <hip/hip_runtime.h>
#include <hip/hip_bf16.h>
#include <cstdint>
#include <cstddef>

// Problem constants (from reference setup_inputs)
#define HH   16
#define BB   4
#define NN   4096
#define DD   1024
#define MM   (BB * NN)      // 16384 rows
#define NC   128            // scan chunks
#define LC   32             // chunk length (NC*LC == NN)
#define EPSV 1e-6f

typedef short short8 __attribute__((ext_vector_type(8)));   // 8 x bf16 (4 VGPRs)
typedef float floatx4 __attribute__((ext_vector_type(4)));

__device__ __forceinline__ void async_copy16(const void* g, void* l) {
    __builtin_amdgcn_global_load_lds(
        (const __attribute__((address_space(1))) void*)g,
        (__attribute__((address_space(3))) void*)l, 16, 0, 0);
}

__device__ __forceinline__ uint2 pack_bf16x4(float a, float b, float c, float d) {
    union { __hip_bfloat16 h[4]; uint2 u; } cv;
    cv.h[0] = __float2bfloat16(a); cv.h[1] = __float2bfloat16(b);
    cv.h[2] = __float2bfloat16(c); cv.h[3] = __float2bfloat16(d);
    return cv.u;
}

__device__ __forceinline__ float sigmoidf(float a) {
    return 1.f / (1.f + expf(-a));
}

// ---- W'[i,j] = o_w[i,j] * nw[j]  (bf16), float4 vectorized ---------------
__global__ void k_wconv(const float* __restrict__ ow, const float* __restrict__ nw,
                        __hip_bfloat16* __restrict__ wp) {
    size_t i4 = (size_t)blockIdx.x * 256 + threadIdx.x;  // over D*D/4
    int j = (int)((i4 * 4) & (DD - 1));
    float4 v = ((const float4*)ow)[i4];
    ((uint2*)wp)[i4] = pack_bf16x4(v.x * nw[j], v.y * nw[j + 1],
                                   v.z * nw[j + 2], v.w * nw[j + 3]);
}

// ---- pass A: chunk-local scan end values (float4 per thread) --------------
__global__ void k_chunk_end(const float* __restrict__ x, const float* __restrict__ ld,
                            float* __restrict__ E) {
    int b = blockIdx.x >> 7, c = blockIdx.x & (NC - 1);
    int j4 = threadIdx.x;                // float4 channel group 0..255
    float lam = sigmoidf(ld[j4 >> 4]);   // 4-ch group never crosses a head
    const float4* xp = (const float4*)(x + ((size_t)(b * NN + c * LC)) * DD) + j4;
    float4 e = {0.f, 0.f, 0.f, 0.f};
    #pragma unroll
    for (int t = 0; t < LC; ++t) {
        float4 v = xp[(size_t)t * (DD / 4)];
        e.x = fmaf(lam, e.x, v.x); e.y = fmaf(lam, e.y, v.y);
        e.z = fmaf(lam, e.z, v.z); e.w = fmaf(lam, e.w, v.w);
    }
    ((float4*)(E + (size_t)blockIdx.x * DD))[j4] = e;
}

// ---- pass B: carry prefix via LDS transpose (coalesced global access) -----
__global__ void k_carry(const float* __restrict__ ld, const float* __restrict__ E,
                        float* __restrict__ P) {
    __shared__ float tile[NC][33];       // +1 pad
    int b = blockIdx.x >> 5, jg = blockIdx.x & 31;   // 4 b x 32 j-groups
    int tid = threadIdx.x;               // 256 threads
    int cc = tid >> 5, jj = tid & 31;
    #pragma unroll
    for (int it = 0; it < 16; ++it) {
        int c = it * 8 + cc;
        tile[c][jj] = E[(size_t)(b * NC + c) * DD + jg * 32 + jj];
    }
    __syncthreads();
    if (tid < 32) {
        int j = jg * 32 + tid;           // 32-ch group never crosses a head
        float lam = sigmoidf(ld[j >> 6]);
        float lamL = lam;                // lam^32 via 5 squarings
        lamL *= lamL; lamL *= lamL; lamL *= lamL; lamL *= lamL; lamL *= lamL;
        float p = 0.f;
        for (int c = 0; c < NC; ++c) {
            float e = tile[c][tid];
            tile[c][tid] = p;            // carry INTO chunk c
            p = fmaf(lamL, p, e);
        }
    }
    __syncthreads();
    #pragma unroll
    for (int it = 0; it < 16; ++it) {
        int c = it * 8 + cc;
        P[(size_t)(b * NC + c) * DD + jg * 32 + jj] = tile[c][jj];
    }
}

// ---- pass C: full scan w/ carry, scale, bf16 store, row sum-sq ------------
// Each block exclusively owns rows [row0, row0+32): no atomics, no memset.
// lam and c_h computed locally (16-lane shuffle dot) -> no meta kernel.
__global__ void k_scan(const float* __restrict__ x, const float* __restrict__ q,
                       const float* __restrict__ k, const float* __restrict__ ld,
                       const float* __restrict__ P, __hip_bfloat16* __restrict__ obf,
                       float* __restrict__ sumsq) {
    __shared__ float ssq[4][LC];
    int b = blockIdx.x >> 7, c = blockIdx.x & (NC - 1);
    int j4 = threadIdx.x;                // 0..255
    int h = j4 >> 4;                     // head (16 float4-groups per head)
    float lam = sigmoidf(ld[h]);
    float4 q4 = ((const float4*)q)[j4];
    float4 k4 = ((const float4*)k)[j4];
    float ch = q4.x * k4.x + q4.y * k4.y + q4.z * k4.z + q4.w * k4.w;
    #pragma unroll
    for (int off = 1; off < 16; off <<= 1) ch += __shfl_xor(ch, off);  // per-head dot
    int row0 = b * NN + c * LC;
    int lane = threadIdx.x & 63, w = threadIdx.x >> 6;
    const float4* xp = (const float4*)(x + (size_t)row0 * DD) + j4;
    float4 y = ((const float4*)(P + (size_t)blockIdx.x * DD))[j4];
    for (int t = 0; t < LC; ++t) {
        float4 v = xp[(size_t)t * (DD / 4)];
        y.x = fmaf(lam, y.x, v.x); y.y = fmaf(lam, y.y, v.y);
        y.z = fmaf(lam, y.z, v.z); y.w = fmaf(lam, y.w, v.w);
        float ox = ch * y.x, oy = ch * y.y, oz = ch * y.z, ow = ch * y.w;
        ((uint2*)(obf + (size_t)(row0 + t) * DD))[j4] = pack_bf16x4(ox, oy, oz, ow);
        float s = ox * ox + oy * oy + oz * oz + ow * ow;
        #pragma unroll
        for (int off = 32; off > 0; off >>= 1) s += __shfl_xor(s, off);
        if (lane == 0) ssq[w][t] = s;
    }
    __syncthreads();
    if (threadIdx.x < LC) {
        int t = threadIdx.x;
        sumsq[row0 + t] = ssq[0][t] + ssq[1][t] + ssq[2][t] + ssq[3][t];
    }
}

// ---- GEMM: out[m,i] = rs[m] * sum_j A[m,j] * W'[i,j] ----------------------
// 256x256 tile, 512 threads (8 waves, 2x4), K pipelined as 32 slabs of K=32.
// 4-slot LDS ring (slot = slab & 3), prefetch 3 slabs ahead, per-slab sync:
// s_waitcnt vmcnt(8) [2 slabs stay in flight] + one s_barrier. vmcnt never
// drains to 0 until the last slab. 2-bit XOR bank swizzle (inverse-swizzled
// global source, linear LDS dest), s_setprio around the 32-MFMA cluster,
// XCD-grouped bm mapping (4 bn-blocks of one bm share an XCD's L2).
//
// LDS slab layout per [slot][mat]: row-major [256 rows][4 octets][8 bf16];
// LDS octet position p holds global octet (p ^ ((row>>1)&3)).
#define GEMM_STAGE(SLOT, S)                                                    \
  do {                                                                         \
    char* _da = (char*)&lds[SLOT][0][0] + w * 1024;                            \
    char* _db = (char*)&lds[SLOT][1][0] + w * 1024;                            \
    _Pragma("unroll") for (int _i = 0; _i < 2; ++_i)                           \
      async_copy16(Ag + (size_t)(m0 + _i * 128 + rr) * 1024 + (S) * 32 + oo * 8, \
                   _da + _i * 8192);                                           \
    _Pragma("unroll") for (int _i = 0; _i < 2; ++_i)                           \
      async_copy16(Wg + (size_t)(n0 + _i * 128 + rr) * 1024 + (S) * 32 + oo * 8, \
                   _db + _i * 8192);                                           \
  } while (0)

#define GEMM_CONSUME(SLOT)                                                     \
  do {                                                                         \
    short8 af[8]; short8 bf[4];                                                \
    const short* _a = &lds[SLOT][0][0];                                        \
    const short* _b = &lds[SLOT][1][0];                                        \
    _Pragma("unroll") for (int mt = 0; mt < 8; ++mt)                           \
      af[mt] = *(const short8*)(_a + (arow_base + mt * 16) * 32 + p_rd * 8);   \
    _Pragma("unroll") for (int nt = 0; nt < 4; ++nt)                           \
      bf[nt] = *(const short8*)(_b + (brow_base + nt * 16) * 32 + p_rd * 8);   \
    asm volatile("s_waitcnt lgkmcnt(0)" ::: "memory");                         \
    __builtin_amdgcn_s_setprio(1);                                             \
    _Pragma("unroll") for (int mt = 0; mt < 8; ++mt) {                         \
      _Pragma("unroll") for (int nt = 0; nt < 4; ++nt)                         \
        acc[mt][nt] = __builtin_amdgcn_mfma_f32_16x16x32_bf16(                 \
            af[mt], bf[nt], acc[mt][nt], 0, 0, 0);                             \
    }                                                                          \
    __builtin_amdgcn_s_setprio(0);                                             \
  } while (0)

__launch_bounds__(512, 2)
__global__ void k_gemm(const __hip_bfloat16* __restrict__ A,
                       const __hip_bfloat16* __restrict__ W,
                       const float* __restrict__ sumsq, float* __restrict__ out) {
    // [slot][mat(A=0,B=1)][256 rows * 4 octets * 8 shorts] = 128 KiB total
    __shared__ __attribute__((aligned(16))) short lds[4][2][256 * 32];
    const int tid = threadIdx.x;
    const int lane = tid & 63, w = tid >> 6;
    const int wm = w >> 2, wn = w & 3;           // 2x4 wave grid, 128x64 each
    const int g = blockIdx.x;                    // 256 blocks = 1 per CU
    const int xcd = g & 7, idx = g >> 3;
    const int bm = xcd * 8 + (idx >> 2);         // 4 bn-blocks of a bm share an XCD
    const int bn = idx & 3;
    const int m0 = bm * 256, n0 = bn * 256;
    const short* Ag = (const short*)A;
    const short* Wg = (const short*)W;

    // staging geometry: slot s16 = i*512 + tid; row r = s16>>2, octet pos p = s16&3;
    // global octet o = p ^ ((r>>1)&3)  (i*128 rows keeps (r>>1)&3 invariant)
    const int rr = tid >> 2;                     // 0..127
    const int oo = (tid & 3) ^ ((rr >> 1) & 3);

    // read-side swizzled octet (frag row base is a multiple of 16)
    const int p_rd = (lane >> 4) ^ (((lane & 15) >> 1) & 3);
    const int arow_base = wm * 128 + (lane & 15);
    const int brow_base = wn * 64 + (lane & 15);

    floatx4 acc[8][4] = {};

    // prologue: stage slabs 0,1,2 (12 loads/thread outstanding)
    GEMM_STAGE(0, 0); GEMM_STAGE(1, 1); GEMM_STAGE(2, 2);

    for (int s = 0; s < 29; ++s) {
        // slab s complete (slabs s+1, s+2 = 8 loads stay in flight)
        asm volatile("s_waitcnt vmcnt(8)" ::: "memory");
        __builtin_amdgcn_s_barrier();
        // slot (s+3)&3 == (s-1)&3: fully read before this barrier (lgkmcnt(0)
        // in iter s-1 precedes it), so restage is safe.
        GEMM_STAGE((s + 3) & 3, s + 3);
        GEMM_CONSUME(s & 3);
    }
    // epilogue slabs 29,30,31: drain 8 -> 4 -> 0
    asm volatile("s_waitcnt vmcnt(8)" ::: "memory");
    __builtin_amdgcn_s_barrier();
    GEMM_CONSUME(1);
    asm volatile("s_waitcnt vmcnt(4)" ::: "memory");
    __builtin_amdgcn_s_barrier();
    GEMM_CONSUME(2);
    asm volatile("s_waitcnt vmcnt(0)" ::: "memory");
    __builtin_amdgcn_s_barrier();
    GEMM_CONSUME(3);

    // epilogue: RMSNorm scale + store. D[m,n]: row = (l>>4)*4+reg, col = l&15
    #pragma unroll
    for (int mt = 0; mt < 8; ++mt) {
        #pragma unroll
        for (int r = 0; r < 4; ++r) {
            int mrow = m0 + wm * 128 + mt * 16 + (lane >> 4) * 4 + r;
            float rs = rsqrtf(sumsq[mrow] * (1.f / 1024.f) + EPSV);
            #pragma unroll
            for (int nt = 0; nt < 4; ++nt) {
                int col = n0 + wn * 64 + nt * 16 + (lane & 15);
                out[(size_t)mrow * 1024 + col] = acc[mt][nt][r] * rs;
            }
        }
    }
}

extern "C" void kernel_launch(void* const* d_in, const int* in_sizes, int n_in,
                              void* d_out, int out_size, void* d_ws, size_t ws_size,
                              hipStream_t stream) {
    const float* x  = (const float*)d_in[0];
    const float* q  = (const float*)d_in[1];
    const float* k  = (const float*)d_in[2];
    const float* ld = (const float*)d_in[3];
    const float* nw = (const float*)d_in[4];
    const float* ow = (const float*)d_in[5];
    float* out = (float*)d_out;

    char* ws = (char*)d_ws;
    // layout (256B aligned): [unused 32f] | sumsq[M]f | E f | P f | W' bf16 | O bf16
    float* sumsq = (float*)(ws + 256);
    float* E     = (float*)(ws + 65792);
    float* P     = (float*)(ws + 2162944);
    __hip_bfloat16* Wp  = (__hip_bfloat16*)(ws + 4260096);
    __hip_bfloat16* Obf = (__hip_bfloat16*)(ws + 6357248);

    k_wconv<<<(DD * DD / 4) / 256, 256, 0, stream>>>(ow, nw, Wp);
    k_chunk_end<<<BB * NC, 256, 0, stream>>>(x, ld, E);
    k_carry<<<BB * 32, 256, 0, stream>>>(ld, E, P);
    k_scan<<<BB * NC, 256, 0, stream>>>(x, q, k, ld, P, Obf, sumsq);
    k_gemm<<<(MM / 256) * (DD / 256), 512, 0, stream>>>(Obf, Wp, sumsq, out);
}